// Round 11
// baseline (140.149 us; speedup 1.0000x reference)
//
#include <hip/hip_runtime.h>
#include <hip/hip_bf16.h>

#define B_ 4
#define N_ 2048
#define C_ 256
#define H_ 4
#define D_ 64

typedef __attribute__((ext_vector_type(8))) short bf16x8;
typedef __attribute__((ext_vector_type(4))) float f32x4;

#define LOG2E 1.4426950408889634f

// f32 -> bf16 round-to-nearest-even (scalar)
static __device__ inline unsigned short f2bf(float f) {
    unsigned u = __builtin_bit_cast(unsigned, f);
    unsigned r = (u + 0x7fffu + ((u >> 16) & 1u)) >> 16;
    return (unsigned short)r;
}
static __device__ inline float bf2f(unsigned short h) {
    unsigned u = ((unsigned)h) << 16;
    return __builtin_bit_cast(float, u);
}
// packed pair f32 -> bf16x2
static __device__ inline unsigned pack2(float a, float b) {
    __hip_bfloat162 h = __float22bfloat162_rn(make_float2(a, b));
    unsigned u;
    __builtin_memcpy(&u, &h, 4);
    return u;
}
static __device__ inline bf16x8 ld_frag(const unsigned short* p) {
    return __builtin_bit_cast(bf16x8, *(const uint4*)p);
}
// async global->LDS DMA, 16B per lane, dest = ldsbase + lane*16
static __device__ inline void gload_lds16(const unsigned short* g, unsigned short* l) {
    __builtin_amdgcn_global_load_lds(
        (const __attribute__((address_space(1))) unsigned int*)(g),
        (__attribute__((address_space(3))) unsigned int*)(l),
        16, 0, 0);
}
// fmax with a DPP-permuted copy (VALU-latency cross-lane, 16-lane row scope)
template<int CTRL>
static __device__ inline float fmax_dpp(float x) {
    int yi = __builtin_amdgcn_update_dpp(0, __builtin_bit_cast(int, x),
                                         CTRL, 0xf, 0xf, true);
    return fmaxf(x, __builtin_bit_cast(float, yi));
}

// ---------------- cvt prepass: x / qkv_w / proj_w -> bf16; Pm -> ext table ----
// ext row (16 shorts) per key n: [ph0,ph1,ph2,pl0,pl1,pl2,ph0,ph1 | ph2,0,..,0]
__global__ __launch_bounds__(256) void cvt_kernel(
    const float* __restrict__ x, const float* __restrict__ qkv_w,
    const float* __restrict__ proj_w, const float* __restrict__ Pm,
    unsigned short* __restrict__ xb, unsigned short* __restrict__ wqb,
    unsigned short* __restrict__ wpb, unsigned short* __restrict__ eb)
{
    const int bid = blockIdx.x, tid = threadIdx.x;
    if (bid >= 1152) {
        const int n = (bid - 1152) * 256 + tid;
        const float* pp = Pm + n * 3;
        float p0 = pp[0], p1 = pp[1], p2 = pp[2];
        unsigned u0 = f2bf(p0), u1 = f2bf(p1), u2 = f2bf(p2);
        unsigned v0 = f2bf(p0 - bf2f((unsigned short)u0));
        unsigned v1 = f2bf(p1 - bf2f((unsigned short)u1));
        unsigned v2 = f2bf(p2 - bf2f((unsigned short)u2));
        uint4 lo, hi;
        lo.x = u0 | (u1 << 16); lo.y = u2 | (v0 << 16);
        lo.z = v1 | (v2 << 16); lo.w = u0 | (u1 << 16);
        hi.x = u2; hi.y = 0u; hi.z = 0u; hi.w = 0u;
        *(uint4*)&eb[n * 16 + 0] = lo;
        *(uint4*)&eb[n * 16 + 8] = hi;
        return;
    }
    const float* s; unsigned short* d; int i;
    if (bid < 1024)      { s = x;      d = xb;  i = (bid * 256 + tid) * 8; }
    else if (bid < 1120) { s = qkv_w;  d = wqb; i = ((bid - 1024) * 256 + tid) * 8; }
    else                 { s = proj_w; d = wpb; i = ((bid - 1120) * 256 + tid) * 8; }
    float4 a = *(const float4*)(s + i);
    float4 b = *(const float4*)(s + i + 4);
    uint4 u;
    u.x = pack2(a.x, a.y); u.y = pack2(a.z, a.w);
    u.z = pack2(b.x, b.y); u.w = pack2(b.z, b.w);
    *(uint4*)(d + i) = u;
}

// ---------------- QKV GEMM: bf16, 128x128 tile, BK=64, DMA double-buffer -----
// global_load_lds with pre-swizzled source (slot ^= row&7), one barrier/iter.
// Q pre-scaled by 0.125*log2e. V written transposed+permuted:
// vt[bh][d][n_perm], perm within 64-block: p = 4*(n&15)+((n>>4)&3).
__global__ __launch_bounds__(256) void qkv_gemm(
    const unsigned short* __restrict__ xb, const unsigned short* __restrict__ wb,
    const float* __restrict__ bias, unsigned short* __restrict__ qb,
    unsigned short* __restrict__ kb, unsigned short* __restrict__ vt)
{
    __shared__ __align__(16) unsigned short As[2][128 * 64]; // 32 KB
    __shared__ __align__(16) unsigned short Bs[2][128 * 64]; // 32 KB
    const int m0 = blockIdx.x * 128, o0 = blockIdx.y * 128;
    const int tid = threadIdx.x;
    const int wave = tid >> 6, lane = tid & 63, quad = lane >> 4, l16 = lane & 15;
    const int wy = wave >> 1, wx = wave & 1;
    const int x7 = l16 & 7;
    const int rl = lane >> 3, sl = lane & 7;      // 8 rows x 8 slots per DMA issue
    const int swz = (sl ^ rl) * 8;

    const unsigned short* aq0 = &xb[(size_t)(m0 + 32 * wave + rl) * 256 + swz];
    const unsigned short* bq0 = &wb[(size_t)(o0 + 32 * wave + rl) * 256 + swz];

    auto ISSUE = [&](int buf, int k0) {
        unsigned short* ad = &As[buf][(32 * wave) * 64];
        unsigned short* bd = &Bs[buf][(32 * wave) * 64];
        #pragma unroll
        for (int i = 0; i < 4; ++i) {
            gload_lds16(aq0 + (size_t)(8 * i) * 256 + k0, ad + (8 * i) * 64);
            gload_lds16(bq0 + (size_t)(8 * i) * 256 + k0, bd + (8 * i) * 64);
        }
    };

    f32x4 acc[4][4];
    #pragma unroll
    for (int i = 0; i < 4; ++i)
        #pragma unroll
        for (int j = 0; j < 4; ++j) acc[i][j] = (f32x4){0.f, 0.f, 0.f, 0.f};

    ISSUE(0, 0);   // prologue: tile 0 in flight

    #pragma unroll
    for (int t = 0; t < 4; ++t) {
        const int cur = t & 1;
        asm volatile("s_waitcnt vmcnt(0)" ::: "memory");   // tile t landed
        __builtin_amdgcn_s_barrier();
        __builtin_amdgcn_sched_barrier(0);
        if (t < 3) ISSUE(cur ^ 1, (t + 1) * 64);           // next tile in flight
        __builtin_amdgcn_s_setprio(1);
        #pragma unroll
        for (int ks = 0; ks < 2; ++ks) {
            bf16x8 a[4], b[4];
            #pragma unroll
            for (int mt = 0; mt < 4; ++mt)
                a[mt] = ld_frag(&As[cur][(wy * 64 + mt * 16 + l16) * 64
                                         + (((ks * 4 + quad) ^ x7) * 8)]);
            #pragma unroll
            for (int nt = 0; nt < 4; ++nt)
                b[nt] = ld_frag(&Bs[cur][(wx * 64 + nt * 16 + l16) * 64
                                         + (((ks * 4 + quad) ^ x7) * 8)]);
            #pragma unroll
            for (int mt = 0; mt < 4; ++mt)
                #pragma unroll
                for (int nt = 0; nt < 4; ++nt)
                    acc[mt][nt] = __builtin_amdgcn_mfma_f32_16x16x32_bf16(a[mt], b[nt], acc[mt][nt], 0, 0, 0);
        }
        __builtin_amdgcn_s_setprio(0);
    }

    const int sec = o0 + wx * 64;            // this wave's 64 output cols
    const int three = sec >> 8;
    const int h = (sec >> 6) & 3;
    const int b = m0 >> 11;
    float bv[4];
    #pragma unroll
    for (int nt = 0; nt < 4; ++nt) bv[nt] = bias[sec + nt * 16 + l16];

    if (three == 2) {
        // V: n = m0 + wy*64 + mt*16 + quad*4 + r; p = 16*quad + 4*r + mt (mt fast)
        const int n64 = (m0 + wy * 64) & 2047;
        const size_t bh64 = ((size_t)b * H_ + h) * 64;
        #pragma unroll
        for (int nt = 0; nt < 4; ++nt) {
            int d = nt * 16 + l16;
            #pragma unroll
            for (int r = 0; r < 4; ++r) {
                ushort4 v;
                v.x = f2bf(acc[0][nt][r] + bv[nt]);
                v.y = f2bf(acc[1][nt][r] + bv[nt]);
                v.z = f2bf(acc[2][nt][r] + bv[nt]);
                v.w = f2bf(acc[3][nt][r] + bv[nt]);
                *(ushort4*)&vt[(bh64 + d) * N_ + n64 + 16 * quad + 4 * r] = v;
            }
        }
    } else {
        unsigned short* dst = (three == 0) ? qb : kb;
        float sc = (three == 0) ? (0.125f * LOG2E) : 1.0f;
        #pragma unroll
        for (int mt = 0; mt < 4; ++mt)
            #pragma unroll
            for (int r = 0; r < 4; ++r) {
                int n = (m0 + wy * 64 + mt * 16 + quad * 4 + r) & 2047;
                size_t rowbase = (((size_t)b * H_ + h) * N_ + n) * D_;
                #pragma unroll
                for (int nt = 0; nt < 4; ++nt)
                    dst[rowbase + nt * 16 + l16] = f2bf((acc[mt][nt][r] + bv[nt]) * sc);
            }
    }
}

// ---------------- Flash attention: 8 waves / 128 queries, split-K x2 ---------
// KVBLK=128: 8 phases of 128 keys (halves per-phase fixed costs vs 64).
// 2-tile software pipeline: phase p does softmax(p-1) + S(p) + PV(p-1).
// Ks double-buffered (32 KB), Vs single (16 KB, R9-style mid-barrier with
// counted vmcnt), Ps 128x128 (32 KB). 80 KB LDS = exactly 2 blocks/CU.
// E (bias B-side) single-buffered in regs, loaded at phase top.
#define LDK 64    // Ks row stride in shorts (128 B, 8 slots of 16 B)
#define LDP 128   // Vs/Ps row stride in shorts (256 B, 16 slots of 16 B)

__global__ __launch_bounds__(512) void attn_kernel(
    const unsigned short* __restrict__ qb, const unsigned short* __restrict__ kb,
    const unsigned short* __restrict__ vt, const unsigned short* __restrict__ eb,
    const float* __restrict__ Rm, const float* __restrict__ Pm,
    const float* __restrict__ ps_ptr,
    unsigned short* __restrict__ Opart, float* __restrict__ ml)
{
    __shared__ __align__(16) unsigned short Ks[2][128 * LDK]; // 32 KB
    __shared__ __align__(16) unsigned short Vs[64 * LDP];     // 16 KB
    __shared__ __align__(16) unsigned short Ps[128 * LDP];    // 32 KB

    const int bh = blockIdx.y;
    const int b = bh >> 2;
    const int i0 = blockIdx.x * 128;
    const int split = blockIdx.z;
    const int tid = threadIdx.x;
    const int wave = tid >> 6, lane = tid & 63;
    const int quad = lane >> 4, l16 = lane & 15;
    const int x7 = l16 & 7;
    const float ps = ps_ptr[0];

    const size_t base = (size_t)bh * N_ * D_;
    const unsigned short* qg = qb + base;
    const unsigned short* kg = kb + base;
    const unsigned short* vg = vt + base;   // rows of length N_

    const int jbeg = split * (N_ / 2);
    // NT = (N_/2)/128 = 8 phases, hard-coded into the 3x2+1 schedule below.

    // ---- DMA source pointers (pre-swizzled), advanced per phase ----
    // K: 16 rows/wave, 2 issues x (8 rows x 8 slots); swizzle key = row&7 = rl
    const int rl = lane >> 3, sl = lane & 7;
    const unsigned short* kp = kg + (size_t)(jbeg + wave * 16 + rl) * D_ + (sl ^ rl) * 8;
    // V: 8 d-rows/wave, 2 issues x (4 rows x 16 slots); swizzle key = d&7
    const int rv = lane >> 4, sv = lane & 15;
    const unsigned short* vp0 = vg + (size_t)(wave * 8 + rv) * N_ + jbeg + (sv ^ rv) * 8;
    const unsigned short* vp1 = vg + (size_t)(wave * 8 + 4 + rv) * N_ + jbeg + (sv ^ (4 + rv)) * 8;
    const unsigned short* ep = eb + (size_t)(jbeg + l16) * 16 + (quad & 1) * 8;

    auto ISSUE_K = [&](int nb) {
        gload_lds16(kp,          &Ks[nb][(wave * 16) * LDK]);
        gload_lds16(kp + 8 * D_, &Ks[nb][(wave * 16 + 8) * LDK]);
        kp += 128 * D_;
    };
    auto ISSUE_V = [&]() {
        gload_lds16(vp0, &Vs[(wave * 8) * LDP]);
        gload_lds16(vp1, &Vs[(wave * 8 + 4) * LDP]);
        vp0 += 128; vp1 += 128;
    };
    bf16x8 e[8];   // current phase's ext B-fragments (single-buffered)
    auto LOAD_E = [&]() {
        #pragma unroll
        for (int t = 0; t < 8; ++t) e[t] = ld_frag(ep + t * 256);
        ep += 128 * 16;
    };

    // prologue: K(0) DMA in flight during Q setup
    ISSUE_K(0);

    // Q A-fragments (pre-scaled by 0.125*log2e)
    const int qrow = i0 + wave * 16 + l16;
    bf16x8 aq[3];
    #pragma unroll
    for (int ks = 0; ks < 2; ++ks)
        aq[ks] = ld_frag(&qg[(size_t)qrow * D_ + ks * 32 + quad * 8]);

    // A-side bias ext: a = ps*log2e*(R_b @ P_qrow), hi/lo split
    {
        float p0 = Pm[qrow * 3 + 0], p1 = Pm[qrow * 3 + 1], p2 = Pm[qrow * 3 + 2];
        float sc = ps * LOG2E;
        unsigned short ah[3], al[3];
        #pragma unroll
        for (int c = 0; c < 3; ++c) {
            float a = (Rm[b * 9 + c * 3 + 0] * p0 + Rm[b * 9 + c * 3 + 1] * p1
                     + Rm[b * 9 + c * 3 + 2] * p2) * sc;
            ah[c] = f2bf(a);
            al[c] = f2bf(a - bf2f(ah[c]));
        }
        bf16x8 ea = (bf16x8){0,0,0,0,0,0,0,0};
        if (quad == 0) {
            ea[0] = (short)ah[0]; ea[1] = (short)ah[1]; ea[2] = (short)ah[2];
            ea[3] = (short)ah[0]; ea[4] = (short)ah[1]; ea[5] = (short)ah[2];
            ea[6] = (short)al[0]; ea[7] = (short)al[1];
        } else if (quad == 1) {
            ea[0] = (short)al[2];
        }
        aq[2] = ea;
    }

    const bf16x8 ones = (bf16x8){0x3F80,0x3F80,0x3F80,0x3F80,0x3F80,0x3F80,0x3F80,0x3F80};

    float m_run = -1e30f;
    f32x4 o_acc[4], lacc;
    #pragma unroll
    for (int t = 0; t < 4; ++t) o_acc[t] = (f32x4){0.f, 0.f, 0.f, 0.f};
    lacc = (f32x4){0.f, 0.f, 0.f, 0.f};

    f32x4 sA[8], sB[8];

    // S (log2-domain logits incl. bias) for the 128-key tile in Ks[kb_]:
    // 16 K-MFMAs then 8 ext-MFMAs (delays first e use; E loaded this phase top)
    auto S_COMPUTE = [&](f32x4 (&sc)[8], int kb_) {
        __builtin_amdgcn_s_setprio(1);
        #pragma unroll
        for (int t = 0; t < 8; ++t) {
            const int rb = (l16 + 16 * t) * LDK;
            f32x4 c = {0.f, 0.f, 0.f, 0.f};
            #pragma unroll
            for (int ks = 0; ks < 2; ++ks) {
                bf16x8 bk = ld_frag(&Ks[kb_][rb + (((ks * 4 + quad) ^ x7) * 8)]);
                c = __builtin_amdgcn_mfma_f32_16x16x32_bf16(aq[ks], bk, c, 0, 0, 0);
            }
            sc[t] = c;
        }
        #pragma unroll
        for (int t = 0; t < 8; ++t)
            sc[t] = __builtin_amdgcn_mfma_f32_16x16x32_bf16(aq[2], e[t], sc[t], 0, 0, 0);
        __builtin_amdgcn_s_setprio(0);
    };

    // online softmax on a 128-key tile's logits (registers) -> Ps
    auto SOFTMAX = [&](f32x4 (&s)[8]) {
        float mt[8];
        #pragma unroll
        for (int t = 0; t < 8; ++t)   // max3-fusable chains
            mt[t] = fmaxf(fmaxf(fmaxf(s[t][0], s[t][1]), s[t][2]), s[t][3]);
        float mx = mt[0];
        #pragma unroll
        for (int t = 1; t < 8; ++t) mx = fmaxf(mx, mt[t]);
        mx = fmax_dpp<0xB1>(mx);    // quad_perm [1,0,3,2]  (xor 1)
        mx = fmax_dpp<0x4E>(mx);    // quad_perm [2,3,0,1]  (xor 2)
        mx = fmax_dpp<0x124>(mx);   // row_ror:4
        mx = fmax_dpp<0x128>(mx);   // row_ror:8
        if (__any(mx > m_run + 8.0f)) {       // defer-max rescale
            float mnew = fmaxf(m_run, mx);
            float alpha = exp2f(m_run - mnew);
            #pragma unroll
            for (int t = 0; t < 4; ++t)
                #pragma unroll
                for (int r = 0; r < 4; ++r)
                    o_acc[t][r] *= alpha;
            #pragma unroll
            for (int r = 0; r < 4; ++r) lacc[r] *= alpha;
            m_run = mnew;
        }
        #pragma unroll
        for (int r = 0; r < 4; ++r) {
            float p0 = exp2f(s[0][r] - m_run), p1 = exp2f(s[1][r] - m_run);
            float p2 = exp2f(s[2][r] - m_run), p3 = exp2f(s[3][r] - m_run);
            float p4 = exp2f(s[4][r] - m_run), p5 = exp2f(s[5][r] - m_run);
            float p6 = exp2f(s[6][r] - m_run), p7 = exp2f(s[7][r] - m_run);
            uint2 w0, w1;
            w0.x = pack2(p0, p1); w0.y = pack2(p2, p3);
            w1.x = pack2(p4, p5); w1.y = pack2(p6, p7);
            const int prow = quad * 4 + r;
            const int a0 = (wave * 16 + prow) * LDP
                         + (((l16 >> 1) ^ (prow & 7)) * 8) + (l16 & 1) * 4;
            *(uint2*)&Ps[a0] = w0;        // key block 0 (slots 0..7)
            *(uint2*)&Ps[a0 + 64] = w1;   // key block 1 (slots 8..15)
        }
    };

    // O += P V; l += P . 1 (ones-MFMA); 128 keys = 4 K-steps
    auto PV = [&]() {
        __builtin_amdgcn_s_setprio(1);
        #pragma unroll
        for (int ks = 0; ks < 4; ++ks) {
            bf16x8 ap = ld_frag(&Ps[(wave * 16 + l16) * LDP
                                    + (((ks * 4 + quad) ^ x7) * 8)]);
            #pragma unroll
            for (int t = 0; t < 4; ++t) {
                bf16x8 bv = ld_frag(&Vs[(l16 + 16 * t) * LDP
                                        + (((ks * 4 + quad) ^ x7) * 8)]);
                o_acc[t] = __builtin_amdgcn_mfma_f32_16x16x32_bf16(ap, bv, o_acc[t], 0, 0, 0);
            }
            lacc = __builtin_amdgcn_mfma_f32_16x16x32_bf16(ap, ones, lacc, 0, 0, 0);
        }
        __builtin_amdgcn_s_setprio(0);
    };

    // phase p: softmax(p-1) + S(p) + PV(p-1), 2 barriers.
    // Issue order pinned [E(p), V(p-1) | fence | K(p+1) | fence]: any stragglers
    // among the last 2 at vmcnt(2) are K-issues, so V is proven landed.
    auto STEP = [&](int cur, bool more, f32x4 (&snew)[8], f32x4 (&sold)[8]) {
        asm volatile("s_waitcnt vmcnt(0)" ::: "memory");
        __builtin_amdgcn_s_barrier();
        __builtin_amdgcn_sched_barrier(0);
        LOAD_E();                     // E(p): consumed late in S_COMPUTE
        ISSUE_V();                    // V(p-1) into Vs (all waves past PV(p-2))
        __builtin_amdgcn_sched_barrier(0);
        if (more) ISSUE_K(cur ^ 1);   // K(p+1)
        __builtin_amdgcn_sched_barrier(0);
        SOFTMAX(sold);                // tile p-1 -> Ps
        S_COMPUTE(snew, cur);         // tile p logits
        __builtin_amdgcn_sched_barrier(0);
        if (more) asm volatile("s_waitcnt vmcnt(2)" ::: "memory");  // V landed
        else      asm volatile("s_waitcnt vmcnt(0)" ::: "memory");
        __builtin_amdgcn_s_barrier(); // all waves' V DMAs landed
        __builtin_amdgcn_sched_barrier(0);
        PV();                         // tile p-1: Ps x Vs
    };

    // --- phase 0 (tile 0): no softmax/PV, no V yet ---
    asm volatile("s_waitcnt vmcnt(0)" ::: "memory");
    __builtin_amdgcn_s_barrier();
    __builtin_amdgcn_sched_barrier(0);
    LOAD_E();        // E(0)
    ISSUE_K(1);      // K(1)
    __builtin_amdgcn_sched_barrier(0);
    S_COMPUTE(sA, 0);

    // --- phases 1..7 (NT=8): 3 pairs + 1 tail ---
    #pragma unroll 1
    for (int it = 0; it < 3; ++it) {
        STEP(1, true, sB, sA);
        STEP(0, true, sA, sB);
    }
    STEP(1, false, sB, sA);

    // --- epilogue: tile 7 softmax + PV ---
    asm volatile("s_waitcnt vmcnt(0)" ::: "memory");
    __builtin_amdgcn_s_barrier();
    __builtin_amdgcn_sched_barrier(0);
    ISSUE_V();       // V(7)
    SOFTMAX(sB);
    asm volatile("s_waitcnt vmcnt(0)" ::: "memory");
    __builtin_amdgcn_s_barrier();
    __builtin_amdgcn_sched_barrier(0);
    PV();

    // store unnormalized partial O (bf16) + (m,l) per row
    const size_t pbase = (size_t)(split * 16 + bh) * N_;
    #pragma unroll
    for (int r = 0; r < 4; ++r) {
        int row = i0 + wave * 16 + quad * 4 + r;
        #pragma unroll
        for (int t = 0; t < 4; ++t)
            Opart[(pbase + row) * D_ + l16 + 16 * t] = f2bf(o_acc[t][r]);
        if (l16 == 0) {
            float2* mlp = (float2*)ml;
            mlp[pbase + row] = make_float2(m_run, lacc[r]);
        }
    }
}

// ---------------- Output projection: fused 2-way merge, BK=64, DMA B ---------
// A-merge on reg path with T14 split (loads issued one compute phase early);
// B tile via DMA double-buffer; one barrier per iter; XOR-swizzled LDS.
__global__ __launch_bounds__(256) void proj_gemm(
    const unsigned short* __restrict__ Opart, const float* __restrict__ ml,
    const unsigned short* __restrict__ wb, const float* __restrict__ bias,
    float* __restrict__ out)
{
    __shared__ __align__(16) unsigned short As[2][64 * 64]; // 16 KB
    __shared__ __align__(16) unsigned short Bs[2][64 * 64]; // 16 KB
    const int m0 = blockIdx.x * 64, o0 = blockIdx.y * 64;
    const int tid = threadIdx.x;
    const int wave = tid >> 6, lane = tid & 63, quad = lane >> 4, l16 = lane & 15;
    const int x7 = l16 & 7;
    const int rl = lane >> 3, sl = lane & 7;
    const int swz = (sl ^ rl) * 8;
    const float2* mlp = (const float2*)ml;

    const int srow = tid >> 2, sc16 = (tid & 3) * 16;   // A-merge: row, 16-col chunk
    const int s0 = (tid & 3) * 2;                       // first of 2 LDS slots
    const int sm = m0 + srow, sb = sm >> 11, sn = sm & 2047;

    // hoist 2-way merge weights per h
    float wgt[4][2];
    #pragma unroll
    for (int h = 0; h < 4; ++h) {
        size_t r1 = (size_t)(sb * 4 + h) * N_ + sn;
        float2 m0v = mlp[r1], m1v = mlp[r1 + 16 * N_];
        float mm = fmaxf(m0v.x, m1v.x);
        float w0 = exp2f(m0v.x - mm), w1 = exp2f(m1v.x - mm);
        float inv = 1.f / (m0v.y * w0 + m1v.y * w1);
        wgt[h][0] = w0 * inv; wgt[h][1] = w1 * inv;
    }

    const unsigned short* bq0 = &wb[(size_t)(o0 + 16 * wave + rl) * 256 + swz];
    auto ISSUE_B = [&](int buf, int k0) {
        unsigned short* bd = &Bs[buf][(16 * wave) * 64];
        gload_lds16(bq0 + k0,           bd);
        gload_lds16(bq0 + 8 * 256 + k0, bd + 8 * 64);
    };

    union U16 { uint4 u; unsigned short s[8]; };
    U16 ar[2][2];   // [split][8-short half] in-flight A sources
    auto LOAD_A = [&](int h) {
        size_t r1 = (size_t)(sb * 4 + h) * N_ + sn;
        #pragma unroll
        for (int s = 0; s < 2; ++s) {
            const unsigned short* p = &Opart[(r1 + (size_t)(16 * s) * N_) * D_ + sc16];
            ar[s][0].u = *(const uint4*)(p);
            ar[s][1].u = *(const uint4*)(p + 8);
        }
    };

    ISSUE_B(0, 0);
    LOAD_A(0);

    f32x4 acc[4];
    #pragma unroll
    for (int j = 0; j < 4; ++j) acc[j] = (f32x4){0.f, 0.f, 0.f, 0.f};

    #pragma unroll
    for (int t = 0; t < 4; ++t) {
        const int cur = t & 1;
        // merge A(t) regs -> As[cur] (swizzled slots)
        {
            float w0 = wgt[t][0], w1 = wgt[t][1];
            #pragma unroll
            for (int j = 0; j < 2; ++j) {
                uint4 mv;
                unsigned* mp = (unsigned*)&mv;
                #pragma unroll
                for (int q = 0; q < 4; ++q) {
                    float lo = bf2f(ar[0][j].s[2*q])   * w0 + bf2f(ar[1][j].s[2*q])   * w1;
                    float hi = bf2f(ar[0][j].s[2*q+1]) * w0 + bf2f(ar[1][j].s[2*q+1]) * w1;
                    mp[q] = pack2(lo, hi);
                }
                *(uint4*)&As[cur][srow * 64 + (((s0 + j) ^ (srow & 7)) * 8)] = mv;
            }
        }
        __syncthreads();   // drains B(t) DMA + A-merge ds_writes
        if (t < 3) {       // T14: next tile's loads issued a full phase early
            ISSUE_B(cur ^ 1, (t + 1) * 64);
            LOAD_A(t + 1);
        }
        __builtin_amdgcn_s_setprio(1);
        #pragma unroll
        for (int ks = 0; ks < 2; ++ks) {
            bf16x8 a = ld_frag(&As[cur][(wave * 16 + l16) * 64
                                        + (((ks * 4 + quad) ^ x7) * 8)]);
            #pragma unroll
            for (int nt = 0; nt < 4; ++nt) {
                bf16x8 b = ld_frag(&Bs[cur][(nt * 16 + l16) * 64
                                            + (((ks * 4 + quad) ^ x7) * 8)]);
                acc[nt] = __builtin_amdgcn_mfma_f32_16x16x32_bf16(a, b, acc[nt], 0, 0, 0);
            }
        }
        __builtin_amdgcn_s_setprio(0);
    }

    float bv[4];
    #pragma unroll
    for (int nt = 0; nt < 4; ++nt) bv[nt] = bias[o0 + nt * 16 + l16];
    #pragma unroll
    for (int r = 0; r < 4; ++r) {
        int m = m0 + wave * 16 + quad * 4 + r;
        #pragma unroll
        for (int nt = 0; nt < 4; ++nt)
            out[(size_t)m * 256 + o0 + nt * 16 + l16] = acc[nt][r] + bv[nt];
    }
}

extern "C" void kernel_launch(void* const* d_in, const int* in_sizes, int n_in,
                              void* d_out, int out_size, void* d_ws, size_t ws_size,
                              hipStream_t stream) {
    const float* x       = (const float*)d_in[0];
    const float* Rm      = (const float*)d_in[1];
    const float* Pm      = (const float*)d_in[2];
    const float* qkv_w   = (const float*)d_in[3];
    const float* qkv_b   = (const float*)d_in[4];
    const float* proj_w  = (const float*)d_in[5];
    const float* proj_b  = (const float*)d_in[6];
    const float* pos_scl = (const float*)d_in[7];
    float* out = (float*)d_out;

    const size_t NE = (size_t)B_ * H_ * N_ * D_;   // 2,097,152
    unsigned short* opart = (unsigned short*)d_ws; // 2 partials = 8 MB
    unsigned short* qb    = opart + 2 * NE;        // 4 MB each
    unsigned short* kb    = qb   + NE;
    unsigned short* vtb   = kb   + NE;
    float*          mlb   = (float*)(vtb + NE);    // 2*16*2048 float2 = 512 KB
    unsigned short* eb    = (unsigned short*)(mlb + (size_t)2 * 16 * N_ * 2); // 64 KB
    unsigned short* wqb   = eb  + 2048 * 16;       // 384 KB
    unsigned short* wpb   = wqb + 768 * 256;       // 128 KB
    unsigned short* xb    = opart;                 // alias: xb dead before attn writes

    cvt_kernel<<<1160, 256, 0, stream>>>(x, qkv_w, proj_w, Pm, xb, wqb, wpb, eb);
    qkv_gemm<<<dim3(64, 6), 256, 0, stream>>>(xb, wqb, qkv_b, qb, kb, vtb);
    attn_kernel<<<dim3(16, 16, 2), 512, 0, stream>>>(qb, kb, vtb, eb, Rm, Pm, pos_scl, opart, mlb);
    proj_gemm<<<dim3(128, 4), 256, 0, stream>>>(opart, mlb, wpb, proj_b, out);
}

// Round 12
// 124.279 us; speedup vs baseline: 1.1277x; 1.1277x over previous
//
#include <hip/hip_runtime.h>
#include <hip/hip_bf16.h>

#define B_ 4
#define N_ 2048
#define C_ 256
#define H_ 4
#define D_ 64

typedef __attribute__((ext_vector_type(8))) short bf16x8;
typedef __attribute__((ext_vector_type(4))) float f32x4;

#define LOG2E 1.4426950408889634f

// f32 -> bf16 round-to-nearest-even (scalar)
static __device__ inline unsigned short f2bf(float f) {
    unsigned u = __builtin_bit_cast(unsigned, f);
    unsigned r = (u + 0x7fffu + ((u >> 16) & 1u)) >> 16;
    return (unsigned short)r;
}
static __device__ inline float bf2f(unsigned short h) {
    unsigned u = ((unsigned)h) << 16;
    return __builtin_bit_cast(float, u);
}
// packed pair f32 -> bf16x2
static __device__ inline unsigned pack2(float a, float b) {
    __hip_bfloat162 h = __float22bfloat162_rn(make_float2(a, b));
    unsigned u;
    __builtin_memcpy(&u, &h, 4);
    return u;
}
static __device__ inline bf16x8 ld_frag(const unsigned short* p) {
    return __builtin_bit_cast(bf16x8, *(const uint4*)p);
}
// async global->LDS DMA, 16B per lane, dest = ldsbase + lane*16
static __device__ inline void gload_lds16(const unsigned short* g, unsigned short* l) {
    __builtin_amdgcn_global_load_lds(
        (const __attribute__((address_space(1))) unsigned int*)(g),
        (__attribute__((address_space(3))) unsigned int*)(l),
        16, 0, 0);
}
// fmax with a DPP-permuted copy (VALU-latency cross-lane, 16-lane row scope)
template<int CTRL>
static __device__ inline float fmax_dpp(float x) {
    int yi = __builtin_amdgcn_update_dpp(0, __builtin_bit_cast(int, x),
                                         CTRL, 0xf, 0xf, true);
    return fmaxf(x, __builtin_bit_cast(float, yi));
}

// ---------------- cvt prepass: x / qkv_w / proj_w -> bf16; Pm -> ext table ----
// ext row (16 shorts) per key n: [ph0,ph1,ph2,pl0,pl1,pl2,ph0,ph1 | ph2,0,..,0]
__global__ __launch_bounds__(256) void cvt_kernel(
    const float* __restrict__ x, const float* __restrict__ qkv_w,
    const float* __restrict__ proj_w, const float* __restrict__ Pm,
    unsigned short* __restrict__ xb, unsigned short* __restrict__ wqb,
    unsigned short* __restrict__ wpb, unsigned short* __restrict__ eb)
{
    const int bid = blockIdx.x, tid = threadIdx.x;
    if (bid >= 1152) {
        const int n = (bid - 1152) * 256 + tid;
        const float* pp = Pm + n * 3;
        float p0 = pp[0], p1 = pp[1], p2 = pp[2];
        unsigned u0 = f2bf(p0), u1 = f2bf(p1), u2 = f2bf(p2);
        unsigned v0 = f2bf(p0 - bf2f((unsigned short)u0));
        unsigned v1 = f2bf(p1 - bf2f((unsigned short)u1));
        unsigned v2 = f2bf(p2 - bf2f((unsigned short)u2));
        uint4 lo, hi;
        lo.x = u0 | (u1 << 16); lo.y = u2 | (v0 << 16);
        lo.z = v1 | (v2 << 16); lo.w = u0 | (u1 << 16);
        hi.x = u2; hi.y = 0u; hi.z = 0u; hi.w = 0u;
        *(uint4*)&eb[n * 16 + 0] = lo;
        *(uint4*)&eb[n * 16 + 8] = hi;
        return;
    }
    const float* s; unsigned short* d; int i;
    if (bid < 1024)      { s = x;      d = xb;  i = (bid * 256 + tid) * 8; }
    else if (bid < 1120) { s = qkv_w;  d = wqb; i = ((bid - 1024) * 256 + tid) * 8; }
    else                 { s = proj_w; d = wpb; i = ((bid - 1120) * 256 + tid) * 8; }
    float4 a = *(const float4*)(s + i);
    float4 b = *(const float4*)(s + i + 4);
    uint4 u;
    u.x = pack2(a.x, a.y); u.y = pack2(a.z, a.w);
    u.z = pack2(b.x, b.y); u.w = pack2(b.z, b.w);
    *(uint4*)(d + i) = u;
}

// ---------------- QKV GEMM: bf16, 128x128 tile, BK=64, DMA double-buffer -----
// global_load_lds with pre-swizzled source (slot ^= row&7), one barrier/iter.
// Q pre-scaled by 0.125*log2e. V written transposed+permuted:
// vt[bh][d][n_perm], perm within 64-block: p = 4*(n&15)+((n>>4)&3).
__global__ __launch_bounds__(256) void qkv_gemm(
    const unsigned short* __restrict__ xb, const unsigned short* __restrict__ wb,
    const float* __restrict__ bias, unsigned short* __restrict__ qb,
    unsigned short* __restrict__ kb, unsigned short* __restrict__ vt)
{
    __shared__ __align__(16) unsigned short As[2][128 * 64]; // 32 KB
    __shared__ __align__(16) unsigned short Bs[2][128 * 64]; // 32 KB
    const int m0 = blockIdx.x * 128, o0 = blockIdx.y * 128;
    const int tid = threadIdx.x;
    const int wave = tid >> 6, lane = tid & 63, quad = lane >> 4, l16 = lane & 15;
    const int wy = wave >> 1, wx = wave & 1;
    const int x7 = l16 & 7;
    const int rl = lane >> 3, sl = lane & 7;      // 8 rows x 8 slots per DMA issue
    const int swz = (sl ^ rl) * 8;

    const unsigned short* aq0 = &xb[(size_t)(m0 + 32 * wave + rl) * 256 + swz];
    const unsigned short* bq0 = &wb[(size_t)(o0 + 32 * wave + rl) * 256 + swz];

    auto ISSUE = [&](int buf, int k0) {
        unsigned short* ad = &As[buf][(32 * wave) * 64];
        unsigned short* bd = &Bs[buf][(32 * wave) * 64];
        #pragma unroll
        for (int i = 0; i < 4; ++i) {
            gload_lds16(aq0 + (size_t)(8 * i) * 256 + k0, ad + (8 * i) * 64);
            gload_lds16(bq0 + (size_t)(8 * i) * 256 + k0, bd + (8 * i) * 64);
        }
    };

    f32x4 acc[4][4];
    #pragma unroll
    for (int i = 0; i < 4; ++i)
        #pragma unroll
        for (int j = 0; j < 4; ++j) acc[i][j] = (f32x4){0.f, 0.f, 0.f, 0.f};

    ISSUE(0, 0);   // prologue: tile 0 in flight

    #pragma unroll
    for (int t = 0; t < 4; ++t) {
        const int cur = t & 1;
        asm volatile("s_waitcnt vmcnt(0)" ::: "memory");   // tile t landed
        __builtin_amdgcn_s_barrier();
        __builtin_amdgcn_sched_barrier(0);
        if (t < 3) ISSUE(cur ^ 1, (t + 1) * 64);           // next tile in flight
        __builtin_amdgcn_s_setprio(1);
        #pragma unroll
        for (int ks = 0; ks < 2; ++ks) {
            bf16x8 a[4], b[4];
            #pragma unroll
            for (int mt = 0; mt < 4; ++mt)
                a[mt] = ld_frag(&As[cur][(wy * 64 + mt * 16 + l16) * 64
                                         + (((ks * 4 + quad) ^ x7) * 8)]);
            #pragma unroll
            for (int nt = 0; nt < 4; ++nt)
                b[nt] = ld_frag(&Bs[cur][(wx * 64 + nt * 16 + l16) * 64
                                         + (((ks * 4 + quad) ^ x7) * 8)]);
            #pragma unroll
            for (int mt = 0; mt < 4; ++mt)
                #pragma unroll
                for (int nt = 0; nt < 4; ++nt)
                    acc[mt][nt] = __builtin_amdgcn_mfma_f32_16x16x32_bf16(a[mt], b[nt], acc[mt][nt], 0, 0, 0);
        }
        __builtin_amdgcn_s_setprio(0);
    }

    const int sec = o0 + wx * 64;            // this wave's 64 output cols
    const int three = sec >> 8;
    const int h = (sec >> 6) & 3;
    const int b = m0 >> 11;
    float bv[4];
    #pragma unroll
    for (int nt = 0; nt < 4; ++nt) bv[nt] = bias[sec + nt * 16 + l16];

    if (three == 2) {
        // V: n = m0 + wy*64 + mt*16 + quad*4 + r; p = 16*quad + 4*r + mt (mt fast)
        const int n64 = (m0 + wy * 64) & 2047;
        const size_t bh64 = ((size_t)b * H_ + h) * 64;
        #pragma unroll
        for (int nt = 0; nt < 4; ++nt) {
            int d = nt * 16 + l16;
            #pragma unroll
            for (int r = 0; r < 4; ++r) {
                ushort4 v;
                v.x = f2bf(acc[0][nt][r] + bv[nt]);
                v.y = f2bf(acc[1][nt][r] + bv[nt]);
                v.z = f2bf(acc[2][nt][r] + bv[nt]);
                v.w = f2bf(acc[3][nt][r] + bv[nt]);
                *(ushort4*)&vt[(bh64 + d) * N_ + n64 + 16 * quad + 4 * r] = v;
            }
        }
    } else {
        unsigned short* dst = (three == 0) ? qb : kb;
        float sc = (three == 0) ? (0.125f * LOG2E) : 1.0f;
        #pragma unroll
        for (int mt = 0; mt < 4; ++mt)
            #pragma unroll
            for (int r = 0; r < 4; ++r) {
                int n = (m0 + wy * 64 + mt * 16 + quad * 4 + r) & 2047;
                size_t rowbase = (((size_t)b * H_ + h) * N_ + n) * D_;
                #pragma unroll
                for (int nt = 0; nt < 4; ++nt)
                    dst[rowbase + nt * 16 + l16] = f2bf((acc[mt][nt][r] + bv[nt]) * sc);
            }
    }
}

// ---------------- Flash attention: 8 waves / 128 queries, split-K x2 ---------
// R7 champion structure (best measured): 2-tile software pipeline, one
// barrier per 64-key tile, Ks/Vs double-buffered DMA (pre-swizzled source),
// ext double-buffered in regs, wave-private Ps. 48 KB LDS, natural VGPR=60.
#define LDK 64   // Ks/Vs/Ps row stride in shorts (128 B, 8 slots of 16 B)

__global__ __launch_bounds__(512) void attn_kernel(
    const unsigned short* __restrict__ qb, const unsigned short* __restrict__ kb,
    const unsigned short* __restrict__ vt, const unsigned short* __restrict__ eb,
    const float* __restrict__ Rm, const float* __restrict__ Pm,
    const float* __restrict__ ps_ptr,
    unsigned short* __restrict__ Opart, float* __restrict__ ml)
{
    __shared__ __align__(16) unsigned short Ks[2][64 * LDK];  // 16 KB
    __shared__ __align__(16) unsigned short Vs[2][64 * LDK];  // 16 KB
    __shared__ __align__(16) unsigned short Ps[128 * LDK];    // 16 KB

    const int bh = blockIdx.y;
    const int b = bh >> 2;
    const int i0 = blockIdx.x * 128;
    const int split = blockIdx.z;
    const int tid = threadIdx.x;
    const int wave = tid >> 6, lane = tid & 63;
    const int quad = lane >> 4, l16 = lane & 15;
    const int x7 = l16 & 7;
    const float ps = ps_ptr[0];

    const size_t base = (size_t)bh * N_ * D_;
    const unsigned short* qg = qb + base;
    const unsigned short* kg = kb + base;
    const unsigned short* vg = vt + base;   // rows of length N_

    const int jbeg = split * (N_ / 2);
    // NT = (N_/2)/64 = 16 tiles, hard-coded into the 7x2+1 step schedule below.

    // ---- DMA source pointers (pre-swizzled), advanced per tile ----
    // 8 waves x 8 rows: one gload_lds16 per wave covers its 8 rows.
    const int rl = lane >> 3, sl = lane & 7;
    const int swz = (sl ^ rl) * 8;
    const unsigned short* kq = kg + (size_t)(jbeg + wave * 8 + rl) * D_ + swz;
    const unsigned short* vq = vg + (size_t)(wave * 8 + rl) * N_ + jbeg + swz;
    const unsigned short* ep = eb + (size_t)(jbeg + l16) * 16 + (quad & 1) * 8;

    auto ISSUE_K = [&](int nb) {
        gload_lds16(kq, &Ks[nb][(wave * 8) * LDK]);
        kq += 64 * D_;
    };
    auto ISSUE_V = [&](int nb) {
        gload_lds16(vq, &Vs[nb][(wave * 8) * LDK]);
        vq += 64;
    };
    auto LOAD_E = [&](bf16x8 (&e)[4]) {
        #pragma unroll
        for (int t = 0; t < 4; ++t) e[t] = ld_frag(ep + t * 256);
        ep += 64 * 16;
    };

    // prologue: K(0) DMA + ext(0) regs
    ISSUE_K(0);
    bf16x8 eA[4], eB[4];
    LOAD_E(eA);

    // Q A-fragments (pre-scaled by 0.125*log2e)
    const int qrow = i0 + wave * 16 + l16;
    bf16x8 aq[3];
    #pragma unroll
    for (int ks = 0; ks < 2; ++ks)
        aq[ks] = ld_frag(&qg[(size_t)qrow * D_ + ks * 32 + quad * 8]);

    // A-side bias ext: a = ps*log2e*(R_b @ P_qrow), hi/lo split
    {
        float p0 = Pm[qrow * 3 + 0], p1 = Pm[qrow * 3 + 1], p2 = Pm[qrow * 3 + 2];
        float sc = ps * LOG2E;
        unsigned short ah[3], al[3];
        #pragma unroll
        for (int c = 0; c < 3; ++c) {
            float a = (Rm[b * 9 + c * 3 + 0] * p0 + Rm[b * 9 + c * 3 + 1] * p1
                     + Rm[b * 9 + c * 3 + 2] * p2) * sc;
            ah[c] = f2bf(a);
            al[c] = f2bf(a - bf2f(ah[c]));
        }
        bf16x8 e = (bf16x8){0,0,0,0,0,0,0,0};
        if (quad == 0) {
            e[0] = (short)ah[0]; e[1] = (short)ah[1]; e[2] = (short)ah[2];
            e[3] = (short)ah[0]; e[4] = (short)ah[1]; e[5] = (short)ah[2];
            e[6] = (short)al[0]; e[7] = (short)al[1];
        } else if (quad == 1) {
            e[0] = (short)al[2];
        }
        aq[2] = e;
    }

    const bf16x8 ones = (bf16x8){0x3F80,0x3F80,0x3F80,0x3F80,0x3F80,0x3F80,0x3F80,0x3F80};

    float m_run = -1e30f;
    f32x4 o_acc[4], lacc;
    #pragma unroll
    for (int t = 0; t < 4; ++t) o_acc[t] = (f32x4){0.f, 0.f, 0.f, 0.f};
    lacc = (f32x4){0.f, 0.f, 0.f, 0.f};

    f32x4 sA[4], sB[4];

    // S (log2-domain logits incl. bias) for the tile in Ks[kb_]
    auto S_COMPUTE = [&](f32x4 (&sc)[4], int kb_, bf16x8 (&ec)[4]) {
        __builtin_amdgcn_s_setprio(1);
        #pragma unroll
        for (int t = 0; t < 4; ++t) {
            const int rb = (l16 + 16 * t) * LDK;
            f32x4 c = {0.f, 0.f, 0.f, 0.f};
            #pragma unroll
            for (int ks = 0; ks < 2; ++ks) {
                bf16x8 bk = ld_frag(&Ks[kb_][rb + (((ks * 4 + quad) ^ x7) * 8)]);
                c = __builtin_amdgcn_mfma_f32_16x16x32_bf16(aq[ks], bk, c, 0, 0, 0);
            }
            c = __builtin_amdgcn_mfma_f32_16x16x32_bf16(aq[2], ec[t], c, 0, 0, 0);
            sc[t] = c;
        }
        __builtin_amdgcn_s_setprio(0);
    };

    // online softmax on a tile's logits (registers) -> Ps (wave-private rows)
    auto SOFTMAX = [&](f32x4 (&s)[4]) {
        float mt[4];
        #pragma unroll
        for (int t = 0; t < 4; ++t)   // max3-fusable chains
            mt[t] = fmaxf(fmaxf(fmaxf(s[t][0], s[t][1]), s[t][2]), s[t][3]);
        float mx = fmaxf(fmaxf(fmaxf(mt[0], mt[1]), mt[2]), mt[3]);
        mx = fmax_dpp<0xB1>(mx);    // quad_perm [1,0,3,2]  (xor 1)
        mx = fmax_dpp<0x4E>(mx);    // quad_perm [2,3,0,1]  (xor 2)
        mx = fmax_dpp<0x124>(mx);   // row_ror:4
        mx = fmax_dpp<0x128>(mx);   // row_ror:8
        if (__any(mx > m_run + 8.0f)) {       // defer-max rescale
            float mnew = fmaxf(m_run, mx);
            float alpha = exp2f(m_run - mnew);
            #pragma unroll
            for (int t = 0; t < 4; ++t)
                #pragma unroll
                for (int r = 0; r < 4; ++r)
                    o_acc[t][r] *= alpha;
            #pragma unroll
            for (int r = 0; r < 4; ++r) lacc[r] *= alpha;
            m_run = mnew;
        }
        #pragma unroll
        for (int r = 0; r < 4; ++r) {
            float p0 = exp2f(s[0][r] - m_run), p1 = exp2f(s[1][r] - m_run);
            float p2 = exp2f(s[2][r] - m_run), p3 = exp2f(s[3][r] - m_run);
            uint2 w;
            w.x = pack2(p0, p1);
            w.y = pack2(p2, p3);
            const int prow = quad * 4 + r;
            *(uint2*)&Ps[(wave * 16 + prow) * LDK
                         + (((l16 >> 1) ^ (prow & 7)) * 8) + (l16 & 1) * 4] = w;
        }
    };

    // O += P V; l += P . 1 (ones-MFMA); reads Vs[vb_]
    auto PV = [&](int vb_) {
        __builtin_amdgcn_s_setprio(1);
        #pragma unroll
        for (int ks = 0; ks < 2; ++ks) {
            bf16x8 ap = ld_frag(&Ps[(wave * 16 + l16) * LDK
                                    + (((ks * 4 + quad) ^ x7) * 8)]);
            #pragma unroll
            for (int t = 0; t < 4; ++t) {
                bf16x8 bv = ld_frag(&Vs[vb_][(l16 + 16 * t) * LDK
                                             + (((ks * 4 + quad) ^ x7) * 8)]);
                o_acc[t] = __builtin_amdgcn_mfma_f32_16x16x32_bf16(ap, bv, o_acc[t], 0, 0, 0);
            }
            lacc = __builtin_amdgcn_mfma_f32_16x16x32_bf16(ap, ones, lacc, 0, 0, 0);
        }
        __builtin_amdgcn_s_setprio(0);
    };

    // pipeline step for tile jt (cur = jt&1): softmax+PV of tile jt-1 overlap
    // the QK MFMAs of tile jt; single barrier per tile.
    auto STEP = [&](int cur, bool more, f32x4 (&snew)[4], f32x4 (&sold)[4],
                    bf16x8 (&euse)[4], bf16x8 (&eload)[4]) {
        asm volatile("s_waitcnt vmcnt(0)" ::: "memory");
        __builtin_amdgcn_s_barrier();
        __builtin_amdgcn_sched_barrier(0);
        if (more) ISSUE_K(cur ^ 1);   // K(jt+1)
        ISSUE_V(cur);                 // V(jt)
        SOFTMAX(sold);                // tile jt-1 -> Ps
        S_COMPUTE(snew, cur, euse);   // tile jt logits (hides Ps lgkm + fills matrix pipe)
        if (more) LOAD_E(eload);      // ext(jt+1)
        PV(cur ^ 1);                  // tile jt-1: Ps x Vs[(jt-1)&1]
    };

    // --- prologue step (tile 0): no softmax/PV yet ---
    asm volatile("s_waitcnt vmcnt(0)" ::: "memory");
    __builtin_amdgcn_s_barrier();
    __builtin_amdgcn_sched_barrier(0);
    ISSUE_K(1);      // K(1)
    ISSUE_V(0);      // V(0)
    S_COMPUTE(sA, 0, eA);
    LOAD_E(eB);      // ext(1)

    // --- tiles 1..15 (NT=16): 7 pairs + 1 tail ---
    #pragma unroll 1
    for (int it = 0; it < 7; ++it) {
        STEP(1, true, sB, sA, eB, eA);
        STEP(0, true, sA, sB, eA, eB);
    }
    STEP(1, false, sB, sA, eB, eA);

    // --- epilogue: finish tile 15 ---
    asm volatile("s_waitcnt vmcnt(0)" ::: "memory");
    __builtin_amdgcn_s_barrier();
    __builtin_amdgcn_sched_barrier(0);
    SOFTMAX(sB);
    PV(1);

    // store unnormalized partial O (bf16) + (m,l) per row
    const size_t pbase = (size_t)(split * 16 + bh) * N_;
    #pragma unroll
    for (int r = 0; r < 4; ++r) {
        int row = i0 + wave * 16 + quad * 4 + r;
        #pragma unroll
        for (int t = 0; t < 4; ++t)
            Opart[(pbase + row) * D_ + l16 + 16 * t] = f2bf(o_acc[t][r]);
        if (l16 == 0) {
            float2* mlp = (float2*)ml;
            mlp[pbase + row] = make_float2(m_run, lacc[r]);
        }
    }
}

// ---------------- Output projection: fused 2-way merge, BK=64, DMA B ---------
// A-merge on reg path with T14 split (loads issued one compute phase early);
// B tile via DMA double-buffer; one barrier per iter; XOR-swizzled LDS.
__global__ __launch_bounds__(256) void proj_gemm(
    const unsigned short* __restrict__ Opart, const float* __restrict__ ml,
    const unsigned short* __restrict__ wb, const float* __restrict__ bias,
    float* __restrict__ out)
{
    __shared__ __align__(16) unsigned short As[2][64 * 64]; // 16 KB
    __shared__ __align__(16) unsigned short Bs[2][64 * 64]; // 16 KB
    const int m0 = blockIdx.x * 64, o0 = blockIdx.y * 64;
    const int tid = threadIdx.x;
    const int wave = tid >> 6, lane = tid & 63, quad = lane >> 4, l16 = lane & 15;
    const int x7 = l16 & 7;
    const int rl = lane >> 3, sl = lane & 7;
    const int swz = (sl ^ rl) * 8;
    const float2* mlp = (const float2*)ml;

    const int srow = tid >> 2, sc16 = (tid & 3) * 16;   // A-merge: row, 16-col chunk
    const int s0 = (tid & 3) * 2;                       // first of 2 LDS slots
    const int sm = m0 + srow, sb = sm >> 11, sn = sm & 2047;

    // hoist 2-way merge weights per h
    float wgt[4][2];
    #pragma unroll
    for (int h = 0; h < 4; ++h) {
        size_t r1 = (size_t)(sb * 4 + h) * N_ + sn;
        float2 m0v = mlp[r1], m1v = mlp[r1 + 16 * N_];
        float mm = fmaxf(m0v.x, m1v.x);
        float w0 = exp2f(m0v.x - mm), w1 = exp2f(m1v.x - mm);
        float inv = 1.f / (m0v.y * w0 + m1v.y * w1);
        wgt[h][0] = w0 * inv; wgt[h][1] = w1 * inv;
    }

    const unsigned short* bq0 = &wb[(size_t)(o0 + 16 * wave + rl) * 256 + swz];
    auto ISSUE_B = [&](int buf, int k0) {
        unsigned short* bd = &Bs[buf][(16 * wave) * 64];
        gload_lds16(bq0 + k0,           bd);
        gload_lds16(bq0 + 8 * 256 + k0, bd + 8 * 64);
    };

    union U16 { uint4 u; unsigned short s[8]; };
    U16 ar[2][2];   // [split][8-short half] in-flight A sources
    auto LOAD_A = [&](int h) {
        size_t r1 = (size_t)(sb * 4 + h) * N_ + sn;
        #pragma unroll
        for (int s = 0; s < 2; ++s) {
            const unsigned short* p = &Opart[(r1 + (size_t)(16 * s) * N_) * D_ + sc16];
            ar[s][0].u = *(const uint4*)(p);
            ar[s][1].u = *(const uint4*)(p + 8);
        }
    };

    ISSUE_B(0, 0);
    LOAD_A(0);

    f32x4 acc[4];
    #pragma unroll
    for (int j = 0; j < 4; ++j) acc[j] = (f32x4){0.f, 0.f, 0.f, 0.f};

    #pragma unroll
    for (int t = 0; t < 4; ++t) {
        const int cur = t & 1;
        // merge A(t) regs -> As[cur] (swizzled slots)
        {
            float w0 = wgt[t][0], w1 = wgt[t][1];
            #pragma unroll
            for (int j = 0; j < 2; ++j) {
                uint4 mv;
                unsigned* mp = (unsigned*)&mv;
                #pragma unroll
                for (int q = 0; q < 4; ++q) {
                    float lo = bf2f(ar[0][j].s[2*q])   * w0 + bf2f(ar[1][j].s[2*q])   * w1;
                    float hi = bf2f(ar[0][j].s[2*q+1]) * w0 + bf2f(ar[1][j].s[2*q+1]) * w1;
                    mp[q] = pack2(lo, hi);
                }
                *(uint4*)&As[cur][srow * 64 + (((s0 + j) ^ (srow & 7)) * 8)] = mv;
            }
        }
        __syncthreads();   // drains B(t) DMA + A-merge ds_writes
        if (t < 3) {       // T14: next tile's loads issued a full phase early
            ISSUE_B(cur ^ 1, (t + 1) * 64);
            LOAD_A(t + 1);
        }
        __builtin_amdgcn_s_setprio(1);
        #pragma unroll
        for (int ks = 0; ks < 2; ++ks) {
            bf16x8 a = ld_frag(&As[cur][(wave * 16 + l16) * 64
                                        + (((ks * 4 + quad) ^ x7) * 8)]);
            #pragma unroll
            for (int nt = 0; nt < 4; ++nt) {
                bf16x8 b = ld_frag(&Bs[cur][(nt * 16 + l16) * 64
                                            + (((ks * 4 + quad) ^ x7) * 8)]);
                acc[nt] = __builtin_amdgcn_mfma_f32_16x16x32_bf16(a, b, acc[nt], 0, 0, 0);
            }
        }
        __builtin_amdgcn_s_setprio(0);
    }

    float bv[4];
    #pragma unroll
    for (int nt = 0; nt < 4; ++nt) bv[nt] = bias[o0 + nt * 16 + l16];
    #pragma unroll
    for (int r = 0; r < 4; ++r) {
        int m = m0 + wave * 16 + quad * 4 + r;
        #pragma unroll
        for (int nt = 0; nt < 4; ++nt)
            out[(size_t)m * 256 + o0 + nt * 16 + l16] = acc[nt][r] + bv[nt];
    }
}

extern "C" void kernel_launch(void* const* d_in, const int* in_sizes, int n_in,
                              void* d_out, int out_size, void* d_ws, size_t ws_size,
                              hipStream_t stream) {
    const float* x       = (const float*)d_in[0];
    const float* Rm      = (const float*)d_in[1];
    const float* Pm      = (const float*)d_in[2];
    const float* qkv_w   = (const float*)d_in[3];
    const float* qkv_b   = (const float*)d_in[4];
    const float* proj_w  = (const float*)d_in[5];
    const float* proj_b  = (const float*)d_in[6];
    const float* pos_scl = (const float*)d_in[7];
    float* out = (float*)d_out;

    const size_t NE = (size_t)B_ * H_ * N_ * D_;   // 2,097,152
    unsigned short* opart = (unsigned short*)d_ws; // 2 partials = 8 MB
    unsigned short* qb    = opart + 2 * NE;        // 4 MB each
    unsigned short* kb    = qb   + NE;
    unsigned short* vtb   = kb   + NE;
    float*          mlb   = (float*)(vtb + NE);    // 2*16*2048 float2 = 512 KB
    unsigned short* eb    = (unsigned short*)(mlb + (size_t)2 * 16 * N_ * 2); // 64 KB
    unsigned short* wqb   = eb  + 2048 * 16;       // 384 KB
    unsigned short* wpb   = wqb + 768 * 256;       // 128 KB
    unsigned short* xb    = opart;                 // alias: xb dead before attn writes

    cvt_kernel<<<1160, 256, 0, stream>>>(x, qkv_w, proj_w, Pm, xb, wqb, wpb, eb);
    qkv_gemm<<<dim3(64, 6), 256, 0, stream>>>(xb, wqb, qkv_b, qb, kb, vtb);
    attn_kernel<<<dim3(16, 16, 2), 512, 0, stream>>>(qb, kb, vtb, eb, Rm, Pm, pos_scl, opart, mlb);
    proj_gemm<<<dim3(128, 4), 256, 0, stream>>>(opart, mlb, wpb, proj_b, out);
}